// Round 1
// baseline (108.688 us; speedup 1.0000x reference)
//
#include <hip/hip_runtime.h>

// Problem constants (fixed by the harness's setup_inputs).
#define VOCAB   32000
#define BB      64
#define LL      200
#define N_ENT   50
#define DD      512
#define F4_ROW  (DD / 4)   // 128 float4 per row

__global__ __launch_bounds__(256) void caption_embed_kernel(
        const int*   __restrict__ ci,     // [B, L] caption_indices
        const float* __restrict__ ents,   // [B, N_ENT, D]
        const float* __restrict__ wemb,   // [V, D]
        const int*   __restrict__ padp,   // scalar pad_token
        const int*   __restrict__ cm,     // [B, L, 1] caption_masks
        float*       __restrict__ out)    // [B, L, D]
{
    // One float4 per thread. total = B*L*128 = 1,638,400 threads, exact grid.
    const int gid = blockIdx.x * 256 + threadIdx.x;
    const int row = gid >> 7;     // which (b, l)
    const int off = gid & 127;    // which float4 within the D=512 row

    const int idx = ci[row];      // broadcast across the 128 threads of this row
    const int m   = cm[row];

    const float4* src;
    if (m == 1) {
        int e = idx - VOCAB;
        if (e < 0 || e >= N_ENT) e = N_ENT - 1;
        const int b = row / LL;   // magic-mul division, cheap
        src = reinterpret_cast<const float4*>(ents + ((long)b * N_ENT + e) * DD);
    } else {
        const int w = (idx >= VOCAB) ? *padp : idx;
        src = reinterpret_cast<const float4*>(wemb + (long)w * DD);
    }

    reinterpret_cast<float4*>(out)[gid] = src[off];
}

extern "C" void kernel_launch(void* const* d_in, const int* in_sizes, int n_in,
                              void* d_out, int out_size, void* d_ws, size_t ws_size,
                              hipStream_t stream) {
    const int*   ci   = (const int*)  d_in[0];
    const float* ents = (const float*)d_in[1];
    const float* wemb = (const float*)d_in[2];
    const int*   padp = (const int*)  d_in[3];
    const int*   cm   = (const int*)  d_in[4];
    float*       out  = (float*)      d_out;

    const int total_f4 = BB * LL * F4_ROW;        // 1,638,400
    const int blocks   = total_f4 / 256;          // 6400, exact
    caption_embed_kernel<<<blocks, 256, 0, stream>>>(ci, ents, wemb, padp, cm, out);
}

// Round 9
// 108.545 us; speedup vs baseline: 1.0013x; 1.0013x over previous
//
#include <hip/hip_runtime.h>

// Problem constants (fixed by the harness's setup_inputs).
#define VOCAB   32000
#define BB      64
#define LL      200
#define N_ENT   50
#define DD      512

// Native clang vector type: __builtin_nontemporal_store requires a real
// vector type, not HIP's float4 class.
typedef float f32x4 __attribute__((ext_vector_type(4)));

// One wave (64 lanes) per output row of D=512 floats (2 KB).
// Each lane handles two float4's: offsets lane and lane+64 (each load
// instruction covers a dense 1 KB segment -> perfectly coalesced).
__global__ __launch_bounds__(256) void caption_embed_kernel(
        const int*   __restrict__ ci,     // [B, L] caption_indices
        const float* __restrict__ ents,   // [B, N_ENT, D]
        const float* __restrict__ wemb,   // [V, D]
        const int*   __restrict__ padp,   // scalar pad_token
        const int*   __restrict__ cm,     // [B, L, 1] caption_masks
        float*       __restrict__ out)    // [B, L, D]
{
    const int gid  = blockIdx.x * 256 + threadIdx.x;
    const int row  = gid >> 6;            // one wave per (b, l) row
    const int lane = gid & 63;

    const int idx = ci[row];              // wave-uniform (HW broadcasts)
    const int m   = cm[row];

    // Entity path address.
    int e = idx - VOCAB;
    if (e < 0 || e >= N_ENT) e = N_ENT - 1;
    const int b = row / LL;               // magic-mul, cheap
    const float* ent_src = ents + ((long)b * N_ENT + e) * DD;

    // Word path address (entity tokens -> pad row).
    const int w = (idx >= VOCAB) ? *padp : idx;   // *padp is a uniform s_load
    const float* word_src = wemb + (long)w * DD;

    // Branchless source select (wave-uniform condition).
    const f32x4* src = reinterpret_cast<const f32x4*>(m == 1 ? ent_src : word_src);

    const f32x4 v0 = src[lane];
    const f32x4 v1 = src[lane + 64];

    f32x4* dst = reinterpret_cast<f32x4*>(out) + (long)row * 128;
    // Output is write-once: bypass L2 so the gather working set stays cached.
    __builtin_nontemporal_store(v0, &dst[lane]);
    __builtin_nontemporal_store(v1, &dst[lane + 64]);
}

extern "C" void kernel_launch(void* const* d_in, const int* in_sizes, int n_in,
                              void* d_out, int out_size, void* d_ws, size_t ws_size,
                              hipStream_t stream) {
    const int*   ci   = (const int*)  d_in[0];
    const float* ents = (const float*)d_in[1];
    const float* wemb = (const float*)d_in[2];
    const int*   padp = (const int*)  d_in[3];
    const int*   cm   = (const int*)  d_in[4];
    float*       out  = (float*)      d_out;

    const int rows   = BB * LL;              // 12800 rows
    const int blocks = rows / 4;             // 4 waves (rows) per 256-thread block -> 3200, exact
    caption_embed_kernel<<<blocks, 256, 0, stream>>>(ci, ents, wemb, padp, cm, out);
}